// Round 1
// baseline (769.885 us; speedup 1.0000x reference)
//
#include <hip/hip_runtime.h>
#include <cstdint>
#include <cstddef>

static constexpr int NN = 50000;   // nodes
static constexpr int NE = 500000;  // edges
static constexpr int NG = 256;     // graphs

// ---------------- CSR build ----------------
__global__ void k_count(const int* __restrict__ dst, int* __restrict__ cnt, int E) {
  int i = blockIdx.x * blockDim.x + threadIdx.x;
  if (i < E) atomicAdd(&cnt[dst[i]], 1);
}

__global__ void k_dinv(const int* __restrict__ cnt, float* __restrict__ dinv, int n) {
  int i = blockIdx.x * blockDim.x + threadIdx.x;
  if (i < n) dinv[i] = rsqrtf((float)(cnt[i] + 1));  // +1 self loop
}

__global__ void k_scan_partial(const int* __restrict__ cnt, int* __restrict__ partial, int n) {
  __shared__ int sdata[1024];
  int tid = threadIdx.x;
  int i = blockIdx.x * 1024 + tid;
  sdata[tid] = (i < n) ? cnt[i] : 0;
  __syncthreads();
  for (int s = 512; s > 0; s >>= 1) {
    if (tid < s) sdata[tid] += sdata[tid + s];
    __syncthreads();
  }
  if (tid == 0) partial[blockIdx.x] = sdata[0];
}

__global__ void k_scan_small(int* __restrict__ partial, int nb) {
  if (threadIdx.x == 0) {
    int run = 0;
    for (int b = 0; b < nb; ++b) { int v = partial[b]; partial[b] = run; run += v; }
  }
}

__global__ void k_scan_final(const int* __restrict__ cnt, const int* __restrict__ partial,
                             int* __restrict__ rowptr, int n) {
  __shared__ int buf[1024];
  int tid = threadIdx.x;
  int i = blockIdx.x * 1024 + tid;
  int v = (i < n) ? cnt[i] : 0;
  buf[tid] = v;
  __syncthreads();
  for (int off = 1; off < 1024; off <<= 1) {
    int t = (tid >= off) ? buf[tid - off] : 0;
    __syncthreads();
    buf[tid] += t;
    __syncthreads();
  }
  int excl = buf[tid] - v + partial[blockIdx.x];
  if (i < n) rowptr[i] = excl;
  if (i == n - 1) rowptr[n] = excl + v;  // total
}

__global__ void k_fill(const int* __restrict__ src, const int* __restrict__ dst,
                       const int* __restrict__ rowptr, int* __restrict__ cur,
                       const float* __restrict__ dinv,
                       int* __restrict__ csr_src, float* __restrict__ csr_val, int E) {
  int i = blockIdx.x * blockDim.x + threadIdx.x;
  if (i < E) {
    int d = dst[i];
    int pos = rowptr[d] + atomicAdd(&cur[d], 1);
    int s = src[i];
    csr_src[pos] = s;
    csr_val[pos] = dinv[s];
  }
}

// ---------------- aggregation: out[v] = dinv[v]*(sum_e dinv[s]*h[s] + dinv[v]*h[v]) ----------------
template<int F, int SIN, int SOUT, int NT>
__global__ void k_agg(const float* __restrict__ hin, const int* __restrict__ rowptr,
                      const int* __restrict__ csr_src, const float* __restrict__ csr_val,
                      const float* __restrict__ dinv, float* __restrict__ out, int n) {
  int wid = (blockIdx.x * blockDim.x + threadIdx.x) >> 6;  // one wave per node
  int lane = threadIdx.x & 63;
  if (wid >= n) return;
  float acc[NT];
#pragma unroll
  for (int t = 0; t < NT; ++t) acc[t] = 0.f;
  int e0 = rowptr[wid], e1 = rowptr[wid + 1];
  for (int e = e0; e < e1; ++e) {
    int s = csr_src[e];
    float w = csr_val[e];
    const float* row = hin + (size_t)s * SIN;
#pragma unroll
    for (int t = 0; t < NT; ++t) {
      int f = lane + 64 * t;
      if (f < F) acc[t] += w * row[f];
    }
  }
  float dv = dinv[wid];
  const float* rowv = hin + (size_t)wid * SIN;
#pragma unroll
  for (int t = 0; t < NT; ++t) {
    int f = lane + 64 * t;
    if (f < F) out[(size_t)wid * SOUT + f] = dv * (acc[t] + dv * rowv[f]);
  }
}

// ---------------- node matmul: C[M,N] = relu(A[M,K] @ W[K,N] + b), strides AS/CS ----------------
template<int K, int AS, int N, int CS, int TN, bool RELU>
__global__ __launch_bounds__(256) void k_mm(const float* __restrict__ A, const float* __restrict__ W,
                                            const float* __restrict__ bias, float* __restrict__ C, int M) {
  __shared__ float as[64 * AS];
  int row0 = blockIdx.x * 64;
  int tid = threadIdx.x;
  // A buffers are padded by >=64 rows, so unguarded tile copy is safe
  for (int i = tid; i < 64 * AS; i += 256) as[i] = A[(size_t)row0 * AS + i];
  __syncthreads();
  int j = tid & 63;
  int r4 = tid >> 6;
  float acc[16][TN];
#pragma unroll
  for (int i = 0; i < 16; ++i)
#pragma unroll
    for (int t = 0; t < TN; ++t) acc[i][t] = 0.f;
  for (int k = 0; k < K; ++k) {
    float wv[TN];
#pragma unroll
    for (int t = 0; t < TN; ++t) {
      int col = j + 64 * t;
      wv[t] = (col < N) ? W[k * N + col] : 0.f;
    }
#pragma unroll
    for (int i = 0; i < 16; ++i) {
      float a = as[(r4 + 4 * i) * AS + k];  // wave-uniform -> LDS broadcast
#pragma unroll
      for (int t = 0; t < TN; ++t) acc[i][t] += a * wv[t];
    }
  }
#pragma unroll
  for (int i = 0; i < 16; ++i) {
    int row = row0 + r4 + 4 * i;
    if (row < M) {
#pragma unroll
      for (int t = 0; t < TN; ++t) {
        int col = j + 64 * t;
        if (col < N) {
          float v = acc[i][t] + bias[col];
          if (RELU) v = fmaxf(v, 0.f);
          C[(size_t)row * CS + col] = v;
        }
      }
    }
  }
}

// ---------------- global max pool (batch sorted) -> transposed g0T[312][256] ----------------
__device__ __forceinline__ int lower_bound(const int* arr, int n, int key) {
  int lo = 0, hi = n;
  while (lo < hi) { int mid = (lo + hi) >> 1; if (arr[mid] < key) lo = mid + 1; else hi = mid; }
  return lo;
}

__global__ void k_pool(const float* __restrict__ h, const int* __restrict__ batch,
                       float* __restrict__ g0T, int n) {
  int g = blockIdx.x;
  int lo = lower_bound(batch, n, g);
  int hi = lower_bound(batch, n, g + 1);
  for (int f = threadIdx.x; f < 312; f += 256) {
    float m = -3.402823466e38f;
    for (int i = lo; i < hi; ++i) m = fmaxf(m, h[(size_t)i * 320 + f]);
    g0T[f * 256 + g] = m;
  }
}

// ---------------- MLP layers on transposed activations AT[K][256] -> CT[N][256] ----------------
template<int K, int N, int TJ, bool RELU>
__global__ void k_mlpT(const float* __restrict__ AT, const float* __restrict__ W,
                       const float* __restrict__ bias, float* __restrict__ CT) {
  int m = threadIdx.x;          // graph index, coalesced
  int j0 = blockIdx.x * TJ;     // output features, wave-uniform -> scalar W loads
  float acc[TJ];
#pragma unroll
  for (int t = 0; t < TJ; ++t) acc[t] = 0.f;
  for (int k = 0; k < K; ++k) {
    float a = AT[k * 256 + m];
#pragma unroll
    for (int t = 0; t < TJ; ++t) acc[t] += a * W[k * N + j0 + t];
  }
#pragma unroll
  for (int t = 0; t < TJ; ++t) {
    float v = acc[t] + bias[j0 + t];
    if (RELU) v = fmaxf(v, 0.f);
    CT[(j0 + t) * 256 + m] = v;
  }
}

__global__ void k_concat_tp(const float* __restrict__ T, const float* __restrict__ P,
                            float* __restrict__ xcT) {
  int m = threadIdx.x;
  xcT[128 * 256 + m] = T[m];
  xcT[129 * 256 + m] = P[m];
}

__global__ void k_final(const float* __restrict__ AT, const float* __restrict__ Wo,
                        const float* __restrict__ bo, float* __restrict__ out) {
  int m = threadIdx.x;
  float acc = 0.f;
  for (int k = 0; k < 512; ++k) acc += AT[k * 256 + m] * Wo[k];
  out[m] = acc + bo[0];
}

// ---------------- launch ----------------
extern "C" void kernel_launch(void* const* d_in, const int* in_sizes, int n_in,
                              void* d_out, int out_size, void* d_ws, size_t ws_size,
                              hipStream_t stream) {
  const float* x   = (const float*)d_in[0];
  const int*   ei  = (const int*)d_in[1];
  const int*   bat = (const int*)d_in[2];
  const float* T   = (const float*)d_in[3];
  const float* P   = (const float*)d_in[4];
  const float* W1  = (const float*)d_in[5];
  const float* b1  = (const float*)d_in[6];
  const float* W2  = (const float*)d_in[7];
  const float* b2  = (const float*)d_in[8];
  const float* W3  = (const float*)d_in[9];
  const float* b3  = (const float*)d_in[10];
  const float* Wg1 = (const float*)d_in[11];
  const float* bg1 = (const float*)d_in[12];
  const float* Wg2 = (const float*)d_in[13];
  const float* bg2 = (const float*)d_in[14];
  const float* Wf1 = (const float*)d_in[15];
  const float* bf1 = (const float*)d_in[16];
  const float* Wf2 = (const float*)d_in[17];
  const float* bf2 = (const float*)d_in[18];
  const float* Wo  = (const float*)d_in[19];
  const float* bo  = (const float*)d_in[20];
  float* out = (float*)d_out;

  char* ws = (char*)d_ws;
  size_t off = 0;
  auto alloc = [&](size_t bytes) -> void* {
    void* p = ws + off;
    off = (off + bytes + 255) & ~(size_t)255;
    return p;
  };
  int*   cnt     = (int*)alloc((size_t)NN * 4);
  int*   rowptr  = (int*)alloc((size_t)(NN + 1) * 4);
  int*   partial = (int*)alloc(64 * 4);
  int*   csr_src = (int*)alloc((size_t)NE * 4);
  float* csr_val = (float*)alloc((size_t)NE * 4);
  float* dinv    = (float*)alloc((size_t)NN * 4);
  float* bufA    = (float*)alloc((size_t)(NN + 64) * 320 * 4);  // h outputs (max stride 320)
  float* bufB    = (float*)alloc((size_t)(NN + 64) * 160 * 4);  // aggregates (max stride 160)
  float* g0T     = (float*)alloc((size_t)312 * 256 * 4);
  float* g1T     = (float*)alloc((size_t)1024 * 256 * 4);
  float* xcT     = (float*)alloc((size_t)130 * 256 * 4);
  float* g3T     = (float*)alloc((size_t)1024 * 256 * 4);
  float* g4T     = (float*)alloc((size_t)512 * 256 * 4);
  (void)ws_size; (void)in_sizes; (void)n_in; (void)out_size;

  const int* srcp = ei;        // edge_index[0]
  const int* dstp = ei + NE;   // edge_index[1]

  hipMemsetAsync(cnt, 0, (size_t)NN * 4, stream);
  k_count<<<(NE + 255) / 256, 256, 0, stream>>>(dstp, cnt, NE);
  k_dinv<<<(NN + 255) / 256, 256, 0, stream>>>(cnt, dinv, NN);
  int nb = (NN + 1023) / 1024;
  k_scan_partial<<<nb, 1024, 0, stream>>>(cnt, partial, NN);
  k_scan_small<<<1, 64, 0, stream>>>(partial, nb);
  k_scan_final<<<nb, 1024, 0, stream>>>(cnt, partial, rowptr, NN);
  hipMemsetAsync(cnt, 0, (size_t)NN * 4, stream);
  k_fill<<<(NE + 255) / 256, 256, 0, stream>>>(srcp, dstp, rowptr, cnt, dinv, csr_src, csr_val, NE);

  const int aggBlocks = (NN * 64 + 255) / 256;  // one wave per node
  const int mmBlocks = (NN + 63) / 64;

  // conv1: aggregate x (stride 78) -> bufB (stride 80); h1 = relu(aggB @ W1 + b1) -> bufA (stride 80)
  k_agg<78, 78, 80, 2><<<aggBlocks, 256, 0, stream>>>(x, rowptr, csr_src, csr_val, dinv, bufB, NN);
  k_mm<78, 80, 78, 80, 2, true><<<mmBlocks, 256, 0, stream>>>(bufB, W1, b1, bufA, NN);
  // conv2
  k_agg<78, 80, 80, 2><<<aggBlocks, 256, 0, stream>>>(bufA, rowptr, csr_src, csr_val, dinv, bufB, NN);
  k_mm<78, 80, 156, 160, 3, true><<<mmBlocks, 256, 0, stream>>>(bufB, W2, b2, bufA, NN);
  // conv3
  k_agg<156, 160, 160, 3><<<aggBlocks, 256, 0, stream>>>(bufA, rowptr, csr_src, csr_val, dinv, bufB, NN);
  k_mm<156, 160, 312, 320, 5, true><<<mmBlocks, 256, 0, stream>>>(bufB, W3, b3, bufA, NN);

  // pool + MLP head (transposed activations)
  k_pool<<<NG, 256, 0, stream>>>(bufA, bat, g0T, NN);
  k_mlpT<312, 1024, 16, true><<<1024 / 16, 256, 0, stream>>>(g0T, Wg1, bg1, g1T);
  k_mlpT<1024, 128, 4, false><<<128 / 4, 256, 0, stream>>>(g1T, Wg2, bg2, xcT);
  k_concat_tp<<<1, 256, 0, stream>>>(T, P, xcT);
  k_mlpT<130, 1024, 16, true><<<1024 / 16, 256, 0, stream>>>(xcT, Wf1, bf1, g3T);
  k_mlpT<1024, 512, 4, true><<<512 / 4, 256, 0, stream>>>(g3T, Wf2, bf2, g4T);
  k_final<<<1, 256, 0, stream>>>(g4T, Wo, bo, out);
}

// Round 3
// 512.238 us; speedup vs baseline: 1.5030x; 1.5030x over previous
//
#include <hip/hip_runtime.h>
#include <cstdint>
#include <cstddef>

static constexpr int NN = 50000;   // nodes
static constexpr int NE = 500000;  // edges
static constexpr int NG = 256;     // graphs

// ---------------- CSR build ----------------
__global__ void k_count(const int* __restrict__ dst, int* __restrict__ cnt, int E) {
  int i = blockIdx.x * blockDim.x + threadIdx.x;
  if (i < E) atomicAdd(&cnt[dst[i]], 1);
}

__global__ void k_dinv(const int* __restrict__ cnt, float* __restrict__ dinv, int n) {
  int i = blockIdx.x * blockDim.x + threadIdx.x;
  if (i < n) dinv[i] = rsqrtf((float)(cnt[i] + 1));  // +1 self loop
}

__global__ void k_scan_partial(const int* __restrict__ cnt, int* __restrict__ partial, int n) {
  __shared__ int sdata[1024];
  int tid = threadIdx.x;
  int i = blockIdx.x * 1024 + tid;
  sdata[tid] = (i < n) ? cnt[i] : 0;
  __syncthreads();
  for (int s = 512; s > 0; s >>= 1) {
    if (tid < s) sdata[tid] += sdata[tid + s];
    __syncthreads();
  }
  if (tid == 0) partial[blockIdx.x] = sdata[0];
}

__global__ void k_scan_small(int* __restrict__ partial, int nb) {
  if (threadIdx.x == 0) {
    int run = 0;
    for (int b = 0; b < nb; ++b) { int v = partial[b]; partial[b] = run; run += v; }
  }
}

__global__ void k_scan_final(const int* __restrict__ cnt, const int* __restrict__ partial,
                             int* __restrict__ rowptr, int n) {
  __shared__ int buf[1024];
  int tid = threadIdx.x;
  int i = blockIdx.x * 1024 + tid;
  int v = (i < n) ? cnt[i] : 0;
  buf[tid] = v;
  __syncthreads();
  for (int off = 1; off < 1024; off <<= 1) {
    int t = (tid >= off) ? buf[tid - off] : 0;
    __syncthreads();
    buf[tid] += t;
    __syncthreads();
  }
  int excl = buf[tid] - v + partial[blockIdx.x];
  if (i < n) rowptr[i] = excl;
  if (i == n - 1) rowptr[n] = excl + v;  // total
}

__global__ void k_fill(const int* __restrict__ src, const int* __restrict__ dst,
                       const int* __restrict__ rowptr, int* __restrict__ cur,
                       const float* __restrict__ dinv,
                       int* __restrict__ csr_src, float* __restrict__ csr_val, int E) {
  int i = blockIdx.x * blockDim.x + threadIdx.x;
  if (i < E) {
    int d = dst[i];
    int pos = rowptr[d] + atomicAdd(&cur[d], 1);
    int s = src[i];
    csr_src[pos] = s;
    csr_val[pos] = dinv[s];
  }
}

// ---------------- aggregation (float4 rows, EPW edges per wave-iter) ----------------
// out[v] = dinv[v]*(sum_e dinv[s]*h[s] + dinv[v]*h[v]) ; optional (+bias, relu)
// Row stride = F4*4 floats (zero-padded). F = true feature count (bias guard).
template<int F4, int EPW, int F, bool BIASRELU>
__global__ void k_agg4(const float* __restrict__ hin, const int* __restrict__ rowptr,
                       const int* __restrict__ csr_src, const float* __restrict__ csr_val,
                       const float* __restrict__ dinv, const float* __restrict__ bias,
                       float* __restrict__ out, int n) {
  int wid = (blockIdx.x * blockDim.x + threadIdx.x) >> 6;  // one wave per node
  int lane = threadIdx.x & 63;
  if (wid >= n) return;
  const float4* hin4 = (const float4*)hin;
  int eoff = lane / F4;
  int fl = lane - eoff * F4;
  float4 acc = make_float4(0.f, 0.f, 0.f, 0.f);
  int e0 = rowptr[wid], e1 = rowptr[wid + 1];
  if (eoff < EPW) {
    for (int e = e0 + eoff; e < e1; e += EPW) {
      int s = csr_src[e];
      float w = csr_val[e];
      float4 v = hin4[(size_t)s * F4 + fl];
      acc.x += w * v.x; acc.y += w * v.y; acc.z += w * v.z; acc.w += w * v.w;
    }
  }
  if (EPW == 3) {  // combine the 3 edge-groups' partials into lanes [0,F4)
    float4 a1, a2;
    a1.x = __shfl(acc.x, lane + F4);     a1.y = __shfl(acc.y, lane + F4);
    a1.z = __shfl(acc.z, lane + F4);     a1.w = __shfl(acc.w, lane + F4);
    a2.x = __shfl(acc.x, lane + 2 * F4); a2.y = __shfl(acc.y, lane + 2 * F4);
    a2.z = __shfl(acc.z, lane + 2 * F4); a2.w = __shfl(acc.w, lane + 2 * F4);
    acc.x += a1.x + a2.x; acc.y += a1.y + a2.y;
    acc.z += a1.z + a2.z; acc.w += a1.w + a2.w;
  }
  if (lane < F4) {
    float dv = dinv[wid];
    float4 sv = hin4[(size_t)wid * F4 + lane];
    acc.x = dv * (acc.x + dv * sv.x);
    acc.y = dv * (acc.y + dv * sv.y);
    acc.z = dv * (acc.z + dv * sv.z);
    acc.w = dv * (acc.w + dv * sv.w);
    if (BIASRELU) {
      float b0 = (lane * 4 + 0 < F) ? bias[lane * 4 + 0] : 0.f;
      float b1 = (lane * 4 + 1 < F) ? bias[lane * 4 + 1] : 0.f;
      float b2 = (lane * 4 + 2 < F) ? bias[lane * 4 + 2] : 0.f;
      float b3 = (lane * 4 + 3 < F) ? bias[lane * 4 + 3] : 0.f;
      acc.x = fmaxf(acc.x + b0, 0.f);
      acc.y = fmaxf(acc.y + b1, 0.f);
      acc.z = fmaxf(acc.z + b2, 0.f);
      acc.w = fmaxf(acc.w + b3, 0.f);
    }
    ((float4*)out)[(size_t)wid * F4 + lane] = acc;
  }
}

// ---------------- node matmul: C[M,CS] = act(A[M,AS(K)] @ W[K,N] + b), zero-pad cols [N,CS) ----------------
// LDS holds A-tile transposed: asT[k][row], row-pad P=68 (16B-aligned rows, conflict-spread staging).
template<int K, int AS, int N, int CS, int TN, bool ADDB, bool RELU>
__global__ __launch_bounds__(256) void k_mm(const float* __restrict__ A, const float* __restrict__ W,
                                            const float* __restrict__ bias, float* __restrict__ C, int M) {
  constexpr int P = 68;
  __shared__ float asT[K * P];
  int row0 = blockIdx.x * 64;
  int tid = threadIdx.x;
  for (int i = tid; i < 64 * K; i += 256) {
    int r = i / K;
    int k = i - r * K;
    int ro = row0 + r;
    asT[k * P + r] = (ro < M) ? A[(size_t)ro * AS + k] : 0.f;
  }
  __syncthreads();
  int j = tid & 63;
  int rg = tid >> 6;  // wave -> rows [rg*16, rg*16+16)
  float acc[16][TN];
#pragma unroll
  for (int i = 0; i < 16; ++i)
#pragma unroll
    for (int t = 0; t < TN; ++t) acc[i][t] = 0.f;
#pragma unroll 2
  for (int k = 0; k < K; ++k) {
    float wv[TN];
#pragma unroll
    for (int t = 0; t < TN; ++t) {
      int col = j + 64 * t;
      wv[t] = (col < N) ? W[k * N + col] : 0.f;
    }
#pragma unroll
    for (int q = 0; q < 4; ++q) {
      float4 a4 = *(const float4*)&asT[k * P + rg * 16 + 4 * q];  // wave-uniform broadcast
#pragma unroll
      for (int t = 0; t < TN; ++t) {
        acc[4 * q + 0][t] += a4.x * wv[t];
        acc[4 * q + 1][t] += a4.y * wv[t];
        acc[4 * q + 2][t] += a4.z * wv[t];
        acc[4 * q + 3][t] += a4.w * wv[t];
      }
    }
  }
#pragma unroll
  for (int i = 0; i < 16; ++i) {
    int row = row0 + rg * 16 + i;
    if (row < M) {
#pragma unroll
      for (int t = 0; t < TN; ++t) {
        int col = j + 64 * t;
        if (col < CS) {
          float v = 0.f;
          if (col < N) {
            v = acc[i][t] + (ADDB ? bias[col] : 0.f);
            if (RELU) v = fmaxf(v, 0.f);
          }
          C[(size_t)row * CS + col] = v;
        }
      }
    }
  }
}

// ---------------- global max pool, 8-way row-split ----------------
__device__ __forceinline__ int lower_bound(const int* arr, int n, int key) {
  int lo = 0, hi = n;
  while (lo < hi) { int mid = (lo + hi) >> 1; if (arr[mid] < key) lo = mid + 1; else hi = mid; }
  return lo;
}

__global__ void k_pool_part(const float* __restrict__ h, const int* __restrict__ batch,
                            float* __restrict__ pp, int n) {
  int g = blockIdx.x & 255;
  int c = blockIdx.x >> 8;  // chunk 0..7
  int lo = lower_bound(batch, n, g);
  int hi = lower_bound(batch, n, g + 1);
  int l2 = lo + (int)(((long long)(hi - lo) * c) / 8);
  int h2 = lo + (int)(((long long)(hi - lo) * (c + 1)) / 8);
  for (int f = threadIdx.x; f < 312; f += 256) {
    float m = -3.402823466e38f;
    for (int i = l2; i < h2; ++i) m = fmaxf(m, h[(size_t)i * 320 + f]);
    pp[((size_t)(c * 312 + f)) * 256 + g] = m;
  }
}

__global__ void k_pool_red(const float* __restrict__ pp, float* __restrict__ g0T) {
  int f = blockIdx.x;
  int g = threadIdx.x;
  float m = -3.402823466e38f;
#pragma unroll
  for (int c = 0; c < 8; ++c) m = fmaxf(m, pp[((size_t)(c * 312 + f)) * 256 + g]);
  g0T[f * 256 + g] = m;
}

// ---------------- MLP on transposed activations, K-split two-stage ----------------
template<int K, int N, int TJ, int KS, int KC>
__global__ void k_mlp_part(const float* __restrict__ AT, const float* __restrict__ W,
                           float* __restrict__ part) {
  constexpr int NB = N / TJ;
  int bj = blockIdx.x % NB;
  int kc = blockIdx.x / NB;
  int j0 = bj * TJ;
  int m = threadIdx.x;
  float acc[TJ];
#pragma unroll
  for (int t = 0; t < TJ; ++t) acc[t] = 0.f;
  int k0 = kc * KC;
  for (int k = k0; k < k0 + KC; ++k) {
    float a = AT[k * 256 + m];
#pragma unroll
    for (int t = 0; t < TJ; ++t) acc[t] += a * W[k * N + j0 + t];
  }
#pragma unroll
  for (int t = 0; t < TJ; ++t) part[((size_t)(kc * N + j0 + t)) * 256 + m] = acc[t];
}

template<int N, int KS, bool RELU>
__global__ void k_mlp_red(const float* __restrict__ part, const float* __restrict__ bias,
                          float* __restrict__ CT) {
  int jcol = blockIdx.x;
  int m = threadIdx.x;
  float s = bias[jcol];
#pragma unroll
  for (int c = 0; c < KS; ++c) s += part[((size_t)(c * N + jcol)) * 256 + m];
  CT[jcol * 256 + m] = RELU ? fmaxf(s, 0.f) : s;
}

__global__ void k_concat_tp(const float* __restrict__ T, const float* __restrict__ P,
                            float* __restrict__ xcT) {
  int m = threadIdx.x;
  xcT[128 * 256 + m] = T[m];
  xcT[129 * 256 + m] = P[m];
}

__global__ void k_final(const float* __restrict__ AT, const float* __restrict__ Wo,
                        const float* __restrict__ bo, float* __restrict__ out) {
  int g = blockIdx.x;
  int lane = threadIdx.x;  // 64
  float acc = 0.f;
#pragma unroll
  for (int u = 0; u < 8; ++u) {
    int k = lane + u * 64;
    acc += AT[k * 256 + g] * Wo[k];
  }
  for (int s = 32; s > 0; s >>= 1) acc += __shfl_down(acc, s);
  if (lane == 0) out[g] = acc + bo[0];
}

// ---------------- launch ----------------
extern "C" void kernel_launch(void* const* d_in, const int* in_sizes, int n_in,
                              void* d_out, int out_size, void* d_ws, size_t ws_size,
                              hipStream_t stream) {
  const float* x   = (const float*)d_in[0];
  const int*   ei  = (const int*)d_in[1];
  const int*   bat = (const int*)d_in[2];
  const float* T   = (const float*)d_in[3];
  const float* P   = (const float*)d_in[4];
  const float* W1  = (const float*)d_in[5];
  const float* b1  = (const float*)d_in[6];
  const float* W2  = (const float*)d_in[7];
  const float* b2  = (const float*)d_in[8];
  const float* W3  = (const float*)d_in[9];
  const float* b3  = (const float*)d_in[10];
  const float* Wg1 = (const float*)d_in[11];
  const float* bg1 = (const float*)d_in[12];
  const float* Wg2 = (const float*)d_in[13];
  const float* bg2 = (const float*)d_in[14];
  const float* Wf1 = (const float*)d_in[15];
  const float* bf1 = (const float*)d_in[16];
  const float* Wf2 = (const float*)d_in[17];
  const float* bf2 = (const float*)d_in[18];
  const float* Wo  = (const float*)d_in[19];
  const float* bo  = (const float*)d_in[20];
  float* out = (float*)d_out;

  char* ws = (char*)d_ws;
  size_t off = 0;
  auto alloc = [&](size_t bytes) -> void* {
    void* p = ws + off;
    off = (off + bytes + 255) & ~(size_t)255;
    return p;
  };
  int*   cnt     = (int*)alloc((size_t)NN * 4);
  int*   rowptr  = (int*)alloc((size_t)(NN + 1) * 4);
  int*   partial = (int*)alloc(64 * 4);
  int*   csr_src = (int*)alloc((size_t)NE * 4);
  float* csr_val = (float*)alloc((size_t)NE * 4);
  float* dinv    = (float*)alloc((size_t)NN * 4);
  float* bufA    = (float*)alloc((size_t)(NN + 64) * 320 * 4);  // h1/h2/h3
  float* bufB    = (float*)alloc((size_t)(NN + 64) * 160 * 4);  // t1/a2/a3
  float* g0T     = (float*)alloc((size_t)312 * 256 * 4);
  float* g1T     = (float*)alloc((size_t)1024 * 256 * 4);
  float* xcT     = (float*)alloc((size_t)130 * 256 * 4);
  float* g3T     = (float*)alloc((size_t)1024 * 256 * 4);
  float* g4T     = (float*)alloc((size_t)512 * 256 * 4);
  float* pp      = (float*)alloc((size_t)8 * 312 * 256 * 4);
  float* mp      = (float*)alloc((size_t)8 * 1024 * 256 * 4);
  (void)ws_size; (void)in_sizes; (void)n_in; (void)out_size;

  const int* srcp = ei;        // edge_index[0]
  const int* dstp = ei + NE;   // edge_index[1]

  hipMemsetAsync(cnt, 0, (size_t)NN * 4, stream);
  k_count<<<(NE + 255) / 256, 256, 0, stream>>>(dstp, cnt, NE);
  k_dinv<<<(NN + 255) / 256, 256, 0, stream>>>(cnt, dinv, NN);
  int nb = (NN + 1023) / 1024;
  k_scan_partial<<<nb, 1024, 0, stream>>>(cnt, partial, NN);
  k_scan_small<<<1, 64, 0, stream>>>(partial, nb);
  k_scan_final<<<nb, 1024, 0, stream>>>(cnt, partial, rowptr, NN);
  hipMemsetAsync(cnt, 0, (size_t)NN * 4, stream);
  k_fill<<<(NE + 255) / 256, 256, 0, stream>>>(srcp, dstp, rowptr, cnt, dinv, csr_src, csr_val, NE);

  const int aggBlocks = (NN * 64) / 256;      // 12500: one wave per node
  const int mmBlocks  = (NN + 63) / 64;       // 782

  // conv1 (matmul-first): t1 = x@W1 (stride 80, zero-pad); h1 = relu(Agg(t1) + b1)
  k_mm<78, 78, 78, 80, 2, false, false><<<mmBlocks, 256, 0, stream>>>(x, W1, nullptr, bufB, NN);
  k_agg4<20, 3, 78, true><<<aggBlocks, 256, 0, stream>>>(bufB, rowptr, csr_src, csr_val, dinv, b1, bufA, NN);
  // conv2 (aggregate-first): a2 = Agg(h1); h2 = relu(a2@W2 + b2)  (stride 160, zero-pad)
  k_agg4<20, 3, 78, false><<<aggBlocks, 256, 0, stream>>>(bufA, rowptr, csr_src, csr_val, dinv, nullptr, bufB, NN);
  k_mm<78, 80, 156, 160, 3, true, true><<<mmBlocks, 256, 0, stream>>>(bufB, W2, b2, bufA, NN);
  // conv3: a3 = Agg(h2); h3 = relu(a3@W3 + b3)  (stride 320, zero-pad)
  k_agg4<40, 1, 156, false><<<aggBlocks, 256, 0, stream>>>(bufA, rowptr, csr_src, csr_val, dinv, nullptr, bufB, NN);
  k_mm<156, 160, 312, 320, 5, true, true><<<mmBlocks, 256, 0, stream>>>(bufB, W3, b3, bufA, NN);

  // pool (8-way split) + MLP head (K-split two-stage)
  k_pool_part<<<NG * 8, 256, 0, stream>>>(bufA, bat, pp, NN);
  k_pool_red<<<312, 256, 0, stream>>>(pp, g0T);

  k_mlp_part<312, 1024, 8, 4, 78><<<(1024 / 8) * 4, 256, 0, stream>>>(g0T, Wg1, mp);
  k_mlp_red<1024, 4, true><<<1024, 256, 0, stream>>>(mp, bg1, g1T);
  k_mlp_part<1024, 128, 4, 8, 128><<<(128 / 4) * 8, 256, 0, stream>>>(g1T, Wg2, mp);
  k_mlp_red<128, 8, false><<<128, 256, 0, stream>>>(mp, bg2, xcT);
  k_concat_tp<<<1, 256, 0, stream>>>(T, P, xcT);
  k_mlp_part<130, 1024, 8, 2, 65><<<(1024 / 8) * 2, 256, 0, stream>>>(xcT, Wf1, mp);
  k_mlp_red<1024, 2, true><<<1024, 256, 0, stream>>>(mp, bf1, g3T);
  k_mlp_part<1024, 512, 8, 8, 128><<<(512 / 8) * 8, 256, 0, stream>>>(g3T, Wf2, mp);
  k_mlp_red<512, 8, true><<<512, 256, 0, stream>>>(mp, bf2, g4T);
  k_final<<<NG, 64, 0, stream>>>(g4T, Wo, bo, out);
}

// Round 4
// 429.076 us; speedup vs baseline: 1.7943x; 1.1938x over previous
//
#include <hip/hip_runtime.h>
#include <cstdint>
#include <cstddef>

static constexpr int NN = 50000;   // nodes
static constexpr int NE = 500000;  // edges
static constexpr int NG = 256;     // graphs

typedef short  frag8  __attribute__((ext_vector_type(8)));   // 8 bf16 (4 VGPRs) MFMA operand
typedef float  f32x4  __attribute__((ext_vector_type(4)));
typedef unsigned short us8 __attribute__((ext_vector_type(8)));
typedef unsigned short us4 __attribute__((ext_vector_type(4)));

__device__ __forceinline__ unsigned short bf16_rne(float f) {
  unsigned u = __builtin_bit_cast(unsigned, f);
  u += 0x7fffu + ((u >> 16) & 1u);
  return (unsigned short)(u >> 16);
}
__device__ __forceinline__ float bf16_to_f(unsigned short h) {
  unsigned u = ((unsigned)h) << 16;
  return __builtin_bit_cast(float, u);
}

// ---------------- CSR build ----------------
__global__ void k_count(const int* __restrict__ dst, int* __restrict__ cnt, int E) {
  int i = blockIdx.x * blockDim.x + threadIdx.x;
  if (i < E) atomicAdd(&cnt[dst[i]], 1);
}

__global__ void k_dinv(const int* __restrict__ cnt, float* __restrict__ dinv, int n) {
  int i = blockIdx.x * blockDim.x + threadIdx.x;
  if (i < n) dinv[i] = rsqrtf((float)(cnt[i] + 1));  // +1 self loop
}

__global__ void k_scan_partial(const int* __restrict__ cnt, int* __restrict__ partial, int n) {
  __shared__ int sdata[1024];
  int tid = threadIdx.x;
  int i = blockIdx.x * 1024 + tid;
  sdata[tid] = (i < n) ? cnt[i] : 0;
  __syncthreads();
  for (int s = 512; s > 0; s >>= 1) {
    if (tid < s) sdata[tid] += sdata[tid + s];
    __syncthreads();
  }
  if (tid == 0) partial[blockIdx.x] = sdata[0];
}

__global__ void k_scan_small(int* __restrict__ partial, int nb) {
  if (threadIdx.x == 0) {
    int run = 0;
    for (int b = 0; b < nb; ++b) { int v = partial[b]; partial[b] = run; run += v; }
  }
}

__global__ void k_scan_final(const int* __restrict__ cnt, const int* __restrict__ partial,
                             int* __restrict__ rowptr, int n) {
  __shared__ int buf[1024];
  int tid = threadIdx.x;
  int i = blockIdx.x * 1024 + tid;
  int v = (i < n) ? cnt[i] : 0;
  buf[tid] = v;
  __syncthreads();
  for (int off = 1; off < 1024; off <<= 1) {
    int t = (tid >= off) ? buf[tid - off] : 0;
    __syncthreads();
    buf[tid] += t;
    __syncthreads();
  }
  int excl = buf[tid] - v + partial[blockIdx.x];
  if (i < n) rowptr[i] = excl;
  if (i == n - 1) rowptr[n] = excl + v;  // total
}

__global__ void k_fill(const int* __restrict__ src, const int* __restrict__ dst,
                       const int* __restrict__ rowptr, int* __restrict__ cur,
                       const float* __restrict__ dinv,
                       int* __restrict__ csr_src, float* __restrict__ csr_val, int E) {
  int i = blockIdx.x * blockDim.x + threadIdx.x;
  if (i < E) {
    int d = dst[i];
    int pos = rowptr[d] + atomicAdd(&cur[d], 1);
    int s = src[i];
    csr_src[pos] = s;
    csr_val[pos] = dinv[s];
  }
}

// ---------------- pad-copy x[NN][78] -> x80[NN][80] (zeros in 78,79) ----------------
__global__ void k_padx(const float* __restrict__ x, float* __restrict__ x80) {
  int idx = blockIdx.x * blockDim.x + threadIdx.x;
  if (idx < NN * 80) {
    int row = idx / 80, c = idx - row * 80;
    x80[idx] = (c < 78) ? x[row * 78 + c] : 0.f;
  }
}

// ---------------- aggregation -> hi/lo bf16 (MFMA A operands) ----------------
// agg[v] = dinv[v]*(sum_e dinv[s]*h[s] + dinv[v]*h[v]); rows stride Kp = KP4*4, zero-padded.
template<int F4IN, int EPW, int KP4>
__global__ void k_agg_dec(const float* __restrict__ hin, const int* __restrict__ rowptr,
                          const int* __restrict__ csr_src, const float* __restrict__ csr_val,
                          const float* __restrict__ dinv,
                          unsigned short* __restrict__ Ah, unsigned short* __restrict__ Al, int n) {
  int wid = (blockIdx.x * blockDim.x + threadIdx.x) >> 6;  // one wave per node
  int lane = threadIdx.x & 63;
  if (wid >= n) return;
  const float4* hin4 = (const float4*)hin;
  int eoff = lane / F4IN;
  int fl = lane - eoff * F4IN;
  float4 acc = make_float4(0.f, 0.f, 0.f, 0.f);
  int e0 = rowptr[wid], e1 = rowptr[wid + 1];
  if (eoff < EPW) {
    for (int e = e0 + eoff; e < e1; e += EPW) {
      int s = csr_src[e];
      float w = csr_val[e];
      float4 v = hin4[(size_t)s * F4IN + fl];
      acc.x += w * v.x; acc.y += w * v.y; acc.z += w * v.z; acc.w += w * v.w;
    }
  }
  if (EPW == 3) {  // combine the 3 edge-groups' partials into lanes [0,F4IN)
    float4 a1, a2;
    a1.x = __shfl(acc.x, lane + F4IN);     a1.y = __shfl(acc.y, lane + F4IN);
    a1.z = __shfl(acc.z, lane + F4IN);     a1.w = __shfl(acc.w, lane + F4IN);
    a2.x = __shfl(acc.x, lane + 2 * F4IN); a2.y = __shfl(acc.y, lane + 2 * F4IN);
    a2.z = __shfl(acc.z, lane + 2 * F4IN); a2.w = __shfl(acc.w, lane + 2 * F4IN);
    acc.x += a1.x + a2.x; acc.y += a1.y + a2.y;
    acc.z += a1.z + a2.z; acc.w += a1.w + a2.w;
  }
  if (lane < KP4) {
    float v[4] = {0.f, 0.f, 0.f, 0.f};
    if (lane < F4IN) {
      float dv = dinv[wid];
      float4 sv = hin4[(size_t)wid * F4IN + lane];
      v[0] = dv * (acc.x + dv * sv.x);
      v[1] = dv * (acc.y + dv * sv.y);
      v[2] = dv * (acc.z + dv * sv.z);
      v[3] = dv * (acc.w + dv * sv.w);
    }
    us4 hi, lo;
#pragma unroll
    for (int j = 0; j < 4; ++j) {
      unsigned short h = bf16_rne(v[j]);
      hi[j] = h;
      lo[j] = bf16_rne(v[j] - bf16_to_f(h));
    }
    size_t base = (size_t)wid * (KP4 * 4) + lane * 4;
    *(us4*)(Ah + base) = hi;
    *(us4*)(Al + base) = lo;
  }
}

// ---------------- W decompose + transpose: W[K][N] f32 -> WT_hi/lo[Np][Kp] bf16 ----------------
template<int K, int N, int Kp, int Np>
__global__ void k_wdec(const float* __restrict__ W, unsigned short* __restrict__ Wh,
                       unsigned short* __restrict__ Wl) {
  int idx = blockIdx.x * blockDim.x + threadIdx.x;
  if (idx >= Np * Kp) return;
  int n = idx / Kp, k = idx - n * Kp;
  float v = (n < N && k < K) ? W[k * N + n] : 0.f;
  unsigned short h = bf16_rne(v);
  Wh[idx] = h;
  Wl[idx] = bf16_rne(v - bf16_to_f(h));
}

// ---------------- MFMA matmul: C[M,Np] = relu(A[M,Kp]@W + bias), split-precision bf16 ----------------
// A hi/lo row-major [.][Kp]; WT hi/lo row-major [Np][Kp]; C f32 stride Np (cols >= N zeroed).
template<int Kp, int Np>
__global__ __launch_bounds__(256) void k_mm_mfma(const unsigned short* __restrict__ Ahp,
                                                 const unsigned short* __restrict__ Alp,
                                                 const unsigned short* __restrict__ Wh,
                                                 const unsigned short* __restrict__ Wl,
                                                 const float* __restrict__ bias,
                                                 float* __restrict__ C, int N) {
  constexpr int NT = Np / 16;
  constexpr int KS = Kp / 32;
  constexpr int PITCH = 40;  // ushorts per LDS row (80B): bank-stride 20 -> <=2-way (free)
  __shared__ unsigned short wlds[2 * Np * PITCH];
  unsigned short* whi = wlds;
  unsigned short* wlo = wlds + Np * PITCH;
  int tid = threadIdx.x;
  int w = tid >> 6, l = tid & 63;
  int m = l & 15, kg = l >> 4;
  int row0 = blockIdx.x * 64;
  f32x4 zero4 = {0.f, 0.f, 0.f, 0.f};
  f32x4 acc[NT];
#pragma unroll
  for (int t = 0; t < NT; ++t) acc[t] = zero4;

  for (int kk = 0; kk < KS; ++kk) {
    // cooperative stage of W k-slice [Np][32] hi+lo into LDS
    for (int i = tid; i < Np * 8; i += 256) {
      int mtx = i / (Np * 4);
      int j = i - mtx * (Np * 4);
      int n = j >> 2, q = j & 3;
      const unsigned short* src = mtx ? Wl : Wh;
      unsigned short* dst = mtx ? wlo : whi;
      *(us8*)&dst[n * PITCH + q * 8] = *(const us8*)&src[n * Kp + kk * 32 + q * 8];
    }
    __syncthreads();
    size_t abase = (size_t)(row0 + 16 * w + m) * Kp + kk * 32 + kg * 8;
    frag8 ah = *(const frag8*)(Ahp + abase);
    frag8 al = *(const frag8*)(Alp + abase);
#pragma unroll
    for (int t = 0; t < NT; ++t) {
      int n = t * 16 + m;
      frag8 bh = *(const frag8*)&whi[n * PITCH + kg * 8];
      frag8 bl = *(const frag8*)&wlo[n * PITCH + kg * 8];
      acc[t] = __builtin_amdgcn_mfma_f32_16x16x32_bf16(ah, bh, acc[t], 0, 0, 0);
      acc[t] = __builtin_amdgcn_mfma_f32_16x16x32_bf16(ah, bl, acc[t], 0, 0, 0);
      acc[t] = __builtin_amdgcn_mfma_f32_16x16x32_bf16(al, bh, acc[t], 0, 0, 0);
    }
    __syncthreads();
  }
  // epilogue: C/D layout (m89-verified): col = lane&15, row = (lane>>4)*4 + reg
#pragma unroll
  for (int t = 0; t < NT; ++t) {
    int col = t * 16 + m;
    float b = (col < N) ? bias[col] : 0.f;
#pragma unroll
    for (int r = 0; r < 4; ++r) {
      int row = row0 + 16 * w + kg * 4 + r;
      float v = fmaxf(acc[t][r] + b, 0.f);
      C[(size_t)row * Np + col] = (col < N) ? v : 0.f;
    }
  }
}

// ---------------- global max pool, 8-way row-split ----------------
__device__ __forceinline__ int lower_bound(const int* arr, int n, int key) {
  int lo = 0, hi = n;
  while (lo < hi) { int mid = (lo + hi) >> 1; if (arr[mid] < key) lo = mid + 1; else hi = mid; }
  return lo;
}

__global__ void k_pool_part(const float* __restrict__ h, const int* __restrict__ batch,
                            float* __restrict__ pp, int n) {
  int g = blockIdx.x & 255;
  int c = blockIdx.x >> 8;  // chunk 0..7
  int lo = lower_bound(batch, n, g);
  int hi = lower_bound(batch, n, g + 1);
  int l2 = lo + (int)(((long long)(hi - lo) * c) / 8);
  int h2 = lo + (int)(((long long)(hi - lo) * (c + 1)) / 8);
  for (int f = threadIdx.x; f < 312; f += 256) {
    float m = -3.402823466e38f;
    for (int i = l2; i < h2; ++i) m = fmaxf(m, h[(size_t)i * 320 + f]);
    pp[((size_t)(c * 312 + f)) * 256 + g] = m;
  }
}

__global__ void k_pool_red(const float* __restrict__ pp, float* __restrict__ g0T) {
  int f = blockIdx.x;
  int g = threadIdx.x;
  float m = -3.402823466e38f;
#pragma unroll
  for (int c = 0; c < 8; ++c) m = fmaxf(m, pp[((size_t)(c * 312 + f)) * 256 + g]);
  g0T[f * 256 + g] = m;
}

// ---------------- MLP on transposed activations, K-split two-stage ----------------
template<int K, int N, int TJ, int KS, int KC>
__global__ void k_mlp_part(const float* __restrict__ AT, const float* __restrict__ W,
                           float* __restrict__ part) {
  constexpr int NB = N / TJ;
  int bj = blockIdx.x % NB;
  int kc = blockIdx.x / NB;
  int j0 = bj * TJ;
  int m = threadIdx.x;
  float acc[TJ];
#pragma unroll
  for (int t = 0; t < TJ; ++t) acc[t] = 0.f;
  int k0 = kc * KC;
  for (int k = k0; k < k0 + KC; ++k) {
    float a = AT[k * 256 + m];
#pragma unroll
    for (int t = 0; t < TJ; ++t) acc[t] += a * W[k * N + j0 + t];
  }
#pragma unroll
  for (int t = 0; t < TJ; ++t) part[((size_t)(kc * N + j0 + t)) * 256 + m] = acc[t];
}

template<int N, int KS, bool RELU>
__global__ void k_mlp_red(const float* __restrict__ part, const float* __restrict__ bias,
                          float* __restrict__ CT) {
  int jcol = blockIdx.x;
  int m = threadIdx.x;
  float s = bias[jcol];
#pragma unroll
  for (int c = 0; c < KS; ++c) s += part[((size_t)(c * N + jcol)) * 256 + m];
  CT[jcol * 256 + m] = RELU ? fmaxf(s, 0.f) : s;
}

__global__ void k_concat_tp(const float* __restrict__ T, const float* __restrict__ P,
                            float* __restrict__ xcT) {
  int m = threadIdx.x;
  xcT[128 * 256 + m] = T[m];
  xcT[129 * 256 + m] = P[m];
}

__global__ void k_final(const float* __restrict__ AT, const float* __restrict__ Wo,
                        const float* __restrict__ bo, float* __restrict__ out) {
  int g = blockIdx.x;
  int lane = threadIdx.x;  // 64
  float acc = 0.f;
#pragma unroll
  for (int u = 0; u < 8; ++u) {
    int k = lane + u * 64;
    acc += AT[k * 256 + g] * Wo[k];
  }
  for (int s = 32; s > 0; s >>= 1) acc += __shfl_down(acc, s);
  if (lane == 0) out[g] = acc + bo[0];
}

// ---------------- launch ----------------
extern "C" void kernel_launch(void* const* d_in, const int* in_sizes, int n_in,
                              void* d_out, int out_size, void* d_ws, size_t ws_size,
                              hipStream_t stream) {
  const float* x   = (const float*)d_in[0];
  const int*   ei  = (const int*)d_in[1];
  const int*   bat = (const int*)d_in[2];
  const float* T   = (const float*)d_in[3];
  const float* P   = (const float*)d_in[4];
  const float* W1  = (const float*)d_in[5];
  const float* b1  = (const float*)d_in[6];
  const float* W2  = (const float*)d_in[7];
  const float* b2  = (const float*)d_in[8];
  const float* W3  = (const float*)d_in[9];
  const float* b3  = (const float*)d_in[10];
  const float* Wg1 = (const float*)d_in[11];
  const float* bg1 = (const float*)d_in[12];
  const float* Wg2 = (const float*)d_in[13];
  const float* bg2 = (const float*)d_in[14];
  const float* Wf1 = (const float*)d_in[15];
  const float* bf1 = (const float*)d_in[16];
  const float* Wf2 = (const float*)d_in[17];
  const float* bf2 = (const float*)d_in[18];
  const float* Wo  = (const float*)d_in[19];
  const float* bo  = (const float*)d_in[20];
  float* out = (float*)d_out;

  char* ws = (char*)d_ws;
  size_t off = 0;
  auto alloc = [&](size_t bytes) -> void* {
    void* p = ws + off;
    off = (off + bytes + 255) & ~(size_t)255;
    return p;
  };
  // R_big: x80/h1 at +0 (16.02MB), h2 at +(NN+64)*80 floats (32.04MB), h3 at +0 (64.08MB)
  // (timeline: x80 dead after agg1; h1 dead after agg2; h2 dead after agg3 -> h3 may overlay)
  float* Rbig    = (float*)alloc((size_t)(NN + 64) * 320 * 4);
  float* x80     = Rbig;
  float* h1      = Rbig;
  float* h2      = Rbig + (size_t)(NN + 64) * 80;
  float* h3      = Rbig;
  unsigned short* aggH = (unsigned short*)alloc((size_t)(NN + 64) * 160 * 2);
  unsigned short* aggL = (unsigned short*)alloc((size_t)(NN + 64) * 160 * 2);
  unsigned short* wtH  = (unsigned short*)alloc((size_t)320 * 160 * 2);
  unsigned short* wtL  = (unsigned short*)alloc((size_t)320 * 160 * 2);
  int*   cnt     = (int*)alloc((size_t)NN * 4);
  int*   rowptr  = (int*)alloc((size_t)(NN + 1) * 4);
  int*   partial = (int*)alloc(64 * 4);
  int*   csr_src = (int*)alloc((size_t)NE * 4);
  float* csr_val = (float*)alloc((size_t)NE * 4);
  float* dinv    = (float*)alloc((size_t)NN * 4);
  float* g0T     = (float*)alloc((size_t)312 * 256 * 4);
  float* g1T     = (float*)alloc((size_t)1024 * 256 * 4);
  float* xcT     = (float*)alloc((size_t)130 * 256 * 4);
  float* g3T     = (float*)alloc((size_t)1024 * 256 * 4);
  float* g4T     = (float*)alloc((size_t)512 * 256 * 4);
  float* ppmp    = (float*)alloc((size_t)8 * 1024 * 256 * 4);  // pool partials, then MLP partials
  float* pp      = ppmp;
  float* mp      = ppmp;
  (void)ws_size; (void)in_sizes; (void)n_in; (void)out_size;

  const int* srcp = ei;        // edge_index[0]
  const int* dstp = ei + NE;   // edge_index[1]

  hipMemsetAsync(cnt, 0, (size_t)NN * 4, stream);
  k_count<<<(NE + 255) / 256, 256, 0, stream>>>(dstp, cnt, NE);
  k_dinv<<<(NN + 255) / 256, 256, 0, stream>>>(cnt, dinv, NN);
  int nb = (NN + 1023) / 1024;
  k_scan_partial<<<nb, 1024, 0, stream>>>(cnt, partial, NN);
  k_scan_small<<<1, 64, 0, stream>>>(partial, nb);
  k_scan_final<<<nb, 1024, 0, stream>>>(cnt, partial, rowptr, NN);
  hipMemsetAsync(cnt, 0, (size_t)NN * 4, stream);
  k_fill<<<(NE + 255) / 256, 256, 0, stream>>>(srcp, dstp, rowptr, cnt, dinv, csr_src, csr_val, NE);

  const int aggBlocks = (NN * 64) / 256;      // one wave per node
  const int mmBlocks  = (NN + 63) / 64;       // 782

  k_padx<<<(NN * 80 + 255) / 256, 256, 0, stream>>>(x, x80);

  // conv1: agg(x80) -> hi/lo Kp=96; h1 = relu(agg@W1 + b1), Np=80 (N=78)
  k_agg_dec<20, 3, 24><<<aggBlocks, 256, 0, stream>>>(x80, rowptr, csr_src, csr_val, dinv, aggH, aggL, NN);
  k_wdec<78, 78, 96, 80><<<(96 * 80 + 255) / 256, 256, 0, stream>>>(W1, wtH, wtL);
  k_mm_mfma<96, 80><<<mmBlocks, 256, 0, stream>>>(aggH, aggL, wtH, wtL, b1, h1, 78);
  // conv2: agg(h1) -> Kp=96; h2 = relu(agg@W2 + b2), Np=160 (N=156)
  k_agg_dec<20, 3, 24><<<aggBlocks, 256, 0, stream>>>(h1, rowptr, csr_src, csr_val, dinv, aggH, aggL, NN);
  k_wdec<78, 156, 96, 160><<<(96 * 160 + 255) / 256, 256, 0, stream>>>(W2, wtH, wtL);
  k_mm_mfma<96, 160><<<mmBlocks, 256, 0, stream>>>(aggH, aggL, wtH, wtL, b2, h2, 156);
  // conv3: agg(h2) -> Kp=160; h3 = relu(agg@W3 + b3), Np=320 (N=312)
  k_agg_dec<40, 1, 40><<<aggBlocks, 256, 0, stream>>>(h2, rowptr, csr_src, csr_val, dinv, aggH, aggL, NN);
  k_wdec<156, 312, 160, 320><<<(160 * 320 + 255) / 256, 256, 0, stream>>>(W3, wtH, wtL);
  k_mm_mfma<160, 320><<<mmBlocks, 256, 0, stream>>>(aggH, aggL, wtH, wtL, b3, h3, 312);

  // pool (8-way split) + MLP head (K-split two-stage)
  k_pool_part<<<NG * 8, 256, 0, stream>>>(h3, bat, pp, NN);
  k_pool_red<<<312, 256, 0, stream>>>(pp, g0T);

  k_mlp_part<312, 1024, 8, 4, 78><<<(1024 / 8) * 4, 256, 0, stream>>>(g0T, Wg1, mp);
  k_mlp_red<1024, 4, true><<<1024, 256, 0, stream>>>(mp, bg1, g1T);
  k_mlp_part<1024, 128, 4, 8, 128><<<(128 / 4) * 8, 256, 0, stream>>>(g1T, Wg2, mp);
  k_mlp_red<128, 8, false><<<128, 256, 0, stream>>>(mp, bg2, xcT);
  k_concat_tp<<<1, 256, 0, stream>>>(T, P, xcT);
  k_mlp_part<130, 1024, 8, 2, 65><<<(1024 / 8) * 2, 256, 0, stream>>>(xcT, Wf1, mp);
  k_mlp_red<1024, 2, true><<<1024, 256, 0, stream>>>(mp, bf1, g3T);
  k_mlp_part<1024, 512, 8, 8, 128><<<(512 / 8) * 8, 256, 0, stream>>>(g3T, Wf2, mp);
  k_mlp_red<512, 8, true><<<512, 256, 0, stream>>>(mp, bf2, g4T);
  k_final<<<NG, 64, 0, stream>>>(g4T, Wo, bo, out);
}